// Round 4
// baseline (242.714 us; speedup 1.0000x reference)
//
#include <hip/hip_runtime.h>
#include <math.h>

#define B_CONST 256
#define V_CONST 128000          // 32000 float4 per row
#define L_CONST 200
#define SLICES  8               // 4000 f4 per block = 256*15 + 160

// ws layout (ints): partial[B*SLICES*4] , subp[B*4] , distp[B*4]
// every slot written unconditionally every launch -> no zero-init needed.

__global__ __launch_bounds__(256) void rank_count_kernel(
    const float* __restrict__ scores,
    const int* __restrict__ labels,
    const int* __restrict__ seqs,
    int* __restrict__ partial,      // [B*SLICES*4]
    int* __restrict__ subp,         // [B*4]
    int* __restrict__ distp)        // [B*4]
{
    const int slice = blockIdx.x;
    const int b     = blockIdx.y;
    const int tid   = threadIdx.x;
    const int wave  = tid >> 6;

    const float* row  = scores + (size_t)b * V_CONST;
    const float4* row4 = (const float4*)row;
    const float predict = row[labels[b]];          // broadcast, overlaps with stream

    // ---- streaming count: 4000 f4 per block, batches of 8 independent loads ----
    const int base = slice * 4000 + tid;           // f4 units, stride 256
    int cnt = 0;

    {   // batch A: k = 0..7
        float4 v0 = row4[base];
        float4 v1 = row4[base + 1 * 256];
        float4 v2 = row4[base + 2 * 256];
        float4 v3 = row4[base + 3 * 256];
        float4 v4 = row4[base + 4 * 256];
        float4 v5 = row4[base + 5 * 256];
        float4 v6 = row4[base + 6 * 256];
        float4 v7 = row4[base + 7 * 256];
        cnt += (v0.x > predict) + (v0.y > predict) + (v0.z > predict) + (v0.w > predict);
        cnt += (v1.x > predict) + (v1.y > predict) + (v1.z > predict) + (v1.w > predict);
        cnt += (v2.x > predict) + (v2.y > predict) + (v2.z > predict) + (v2.w > predict);
        cnt += (v3.x > predict) + (v3.y > predict) + (v3.z > predict) + (v3.w > predict);
        cnt += (v4.x > predict) + (v4.y > predict) + (v4.z > predict) + (v4.w > predict);
        cnt += (v5.x > predict) + (v5.y > predict) + (v5.z > predict) + (v5.w > predict);
        cnt += (v6.x > predict) + (v6.y > predict) + (v6.z > predict) + (v6.w > predict);
        cnt += (v7.x > predict) + (v7.y > predict) + (v7.z > predict) + (v7.w > predict);
    }
    {   // batch B: k = 8..14, plus remainder (tid < 160) at f4 3840..3999
        float4 v0 = row4[base + 8  * 256];
        float4 v1 = row4[base + 9  * 256];
        float4 v2 = row4[base + 10 * 256];
        float4 v3 = row4[base + 11 * 256];
        float4 v4 = row4[base + 12 * 256];
        float4 v5 = row4[base + 13 * 256];
        float4 v6 = row4[base + 14 * 256];
        if (tid < 160) {
            float4 v7 = row4[slice * 4000 + 3840 + tid];
            cnt += (v7.x > predict) + (v7.y > predict) + (v7.z > predict) + (v7.w > predict);
        }
        cnt += (v0.x > predict) + (v0.y > predict) + (v0.z > predict) + (v0.w > predict);
        cnt += (v1.x > predict) + (v1.y > predict) + (v1.z > predict) + (v1.w > predict);
        cnt += (v2.x > predict) + (v2.y > predict) + (v2.z > predict) + (v2.w > predict);
        cnt += (v3.x > predict) + (v3.y > predict) + (v3.z > predict) + (v3.w > predict);
        cnt += (v4.x > predict) + (v4.y > predict) + (v4.z > predict) + (v4.w > predict);
        cnt += (v5.x > predict) + (v5.y > predict) + (v5.z > predict) + (v5.w > predict);
        cnt += (v6.x > predict) + (v6.y > predict) + (v6.z > predict) + (v6.w > predict);
    }

    // wave64 shuffle reduce -> private slot, no atomics
    #pragma unroll
    for (int off = 32; off > 0; off >>= 1)
        cnt += __shfl_down(cnt, off, 64);
    if ((tid & 63) == 0)
        partial[(b * SLICES + slice) * 4 + wave] = cnt;

    // ---- history dedup + correction (slice-0 blocks only, waves 0..3) ----
    if (slice == 0) {
        int dflag = 0, sflag = 0;
        if (tid < L_CONST) {
            const int* srow = seqs + b * L_CONST;
            const int s = srow[tid];
            bool first = true;
            for (int j = 0; j < tid; ++j)
                if (srow[j] == s) { first = false; break; }
            if (first) {
                dflag = 1;
                sflag = (row[s] > predict) ? 1 : 0;
            }
        }
        #pragma unroll
        for (int off = 32; off > 0; off >>= 1) {
            dflag += __shfl_down(dflag, off, 64);
            sflag += __shfl_down(sflag, off, 64);
        }
        if ((tid & 63) == 0) {
            distp[b * 4 + wave] = dflag;
            subp [b * 4 + wave] = sflag;
        }
    }
}

// single block, 256 threads (one per row)
__global__ __launch_bounds__(256) void finalize_kernel(
    const int* __restrict__ partial,
    const int* __restrict__ subp,
    const int* __restrict__ distp,
    float* __restrict__ out)
{
    const int b = threadIdx.x;
    int gt = 0;
    #pragma unroll
    for (int s = 0; s < SLICES * 4; ++s) gt += partial[b * SLICES * 4 + s];
    int sub = 0, dist = 0;
    #pragma unroll
    for (int w = 0; w < 4; ++w) { sub += subp[b * 4 + w]; dist += distp[b * 4 + w]; }

    const float rank  = (float)(gt - sub);
    const float valid = (float)(V_CONST - dist);

    const float ks[5] = {1.0f, 5.0f, 10.0f, 20.0f, 50.0f};
    float vals[12];
    const float invlog = 1.0f / log2f(rank + 2.0f);
    #pragma unroll
    for (int i = 0; i < 5; ++i) {
        const float ind = (rank < ks[i]) ? 1.0f : 0.0f;
        vals[2 * i]     = ind * invlog;   // NDCG@k
        vals[2 * i + 1] = ind;            // Recall@k
    }
    vals[10] = 1.0f / (rank + 1.0f);      // MRR
    vals[11] = 1.0f - rank / valid;       // AUC-like

    __shared__ float red[4];
    for (int q = 0; q < 12; ++q) {
        float v = vals[q];
        #pragma unroll
        for (int off = 32; off > 0; off >>= 1)
            v += __shfl_down(v, off, 64);
        if ((b & 63) == 0) red[b >> 6] = v;
        __syncthreads();
        if (b == 0) out[q] = (red[0] + red[1] + red[2] + red[3]) * (1.0f / B_CONST);
        __syncthreads();
    }
    if (b == 0) out[12] = 0.0f;
}

extern "C" void kernel_launch(void* const* d_in, const int* in_sizes, int n_in,
                              void* d_out, int out_size, void* d_ws, size_t ws_size,
                              hipStream_t stream) {
    const float* scores = (const float*)d_in[0];
    const int*   labels = (const int*)d_in[1];
    const int*   seqs   = (const int*)d_in[2];
    float* out = (float*)d_out;
    int*   ws  = (int*)d_ws;

    int* partial = ws;                                   // B*SLICES*4
    int* subp    = ws + B_CONST * SLICES * 4;            // B*4
    int* distp   = ws + B_CONST * SLICES * 4 + B_CONST * 4;  // B*4

    rank_count_kernel<<<dim3(SLICES, B_CONST), 256, 0, stream>>>(
        scores, labels, seqs, partial, subp, distp);
    finalize_kernel<<<1, 256, 0, stream>>>(partial, subp, distp, out);
}

// Round 5
// 204.314 us; speedup vs baseline: 1.1880x; 1.1880x over previous
//
#include <hip/hip_runtime.h>
#include <math.h>

#define B_CONST 256
#define V_CONST 128000          // floats per row
#define L_CONST 200
#define SLICES  5               // 25600 floats per block = 25 tiles x 1024
#define NTILES  25
#define NBUF    4               // LDS ring: 4 x 4KB

// ws layout (ints): partial[B*SLICES*4], subp[B*4], distp[B*4] — all written
// unconditionally every launch, no zero-init needed.

__device__ __forceinline__ void load_lds16(const float* g, float4* l) {
    // DMA global->LDS, 16B per lane. LDS dest = wave-uniform base + lane*16.
    __builtin_amdgcn_global_load_lds(
        (const __attribute__((address_space(1))) void*)g,
        (__attribute__((address_space(3))) void*)l, 16, 0, 0);
}

#define WAITV(n) asm volatile("s_waitcnt vmcnt(" #n ")" ::: "memory")

__global__ __launch_bounds__(256) void rank_count_kernel(
    const float* __restrict__ scores,
    const int* __restrict__ labels,
    const int* __restrict__ seqs,
    int* __restrict__ partial,      // [B*SLICES*4]
    int* __restrict__ subp,         // [B*4]
    int* __restrict__ distp)        // [B*4]
{
    const int slice = blockIdx.x;
    const int b     = blockIdx.y;
    const int tid   = threadIdx.x;
    const int w     = tid >> 6;
    const int lane  = tid & 63;

    __shared__ float4 buf[NBUF][256];    // 4 x 4KB ring; wave w owns f4 [w*64, w*64+64)
    __shared__ int s_seq[L_CONST];

    const float* row = scores + (size_t)b * V_CONST;
    const float predict = row[labels[b]];            // broadcast
    if (slice == 0 && tid < L_CONST) s_seq[tid] = seqs[b * L_CONST + tid];
    // Drain all VGPR-bound vmem now so the steady loop's vmcnt tracks ONLY
    // the global_load_lds fills (barrier emits s_waitcnt vmcnt(0) first).
    __syncthreads();

    const float* chunk = row + slice * (V_CONST / SLICES);   // 25600 floats

    // fill tile t: this wave stages its own 1KB (64 f4) slice
#define FILL(t) load_lds16(chunk + (t) * 1024 + w * 256 + lane * 4, \
                           &buf[(t) & (NBUF - 1)][w * 64])

    int cnt = 0;
#define COUNT(t) do { \
        float4 v = buf[(t) & (NBUF - 1)][w * 64 + lane]; \
        cnt += (v.x > predict) + (v.y > predict) + (v.z > predict) + (v.w > predict); \
    } while (0)

    FILL(0); FILL(1); FILL(2);
    for (int t = 0; t < NTILES - 3; ++t) {
        FILL(t + 3);
        WAITV(3);            // tile t complete (<=3 newer fills outstanding)
        COUNT(t);
    }
    WAITV(2); COUNT(NTILES - 3);
    WAITV(1); COUNT(NTILES - 2);
    WAITV(0); COUNT(NTILES - 1);

    // wave64 shuffle reduce -> private slot, no atomics
    #pragma unroll
    for (int off = 32; off > 0; off >>= 1)
        cnt += __shfl_down(cnt, off, 64);
    if (lane == 0)
        partial[(b * SLICES + slice) * 4 + w] = cnt;

    // ---- history dedup + correction (slice-0 blocks only) ----
    if (slice == 0) {
        int dflag = 0, sflag = 0;
        if (tid < L_CONST) {
            const int s = s_seq[tid];
            const float sv = row[s];                 // issue gather early
            bool first = true;
            for (int j = 0; j < tid; ++j)
                if (s_seq[j] == s) { first = false; break; }
            if (first) {
                dflag = 1;
                sflag = (sv > predict) ? 1 : 0;
            }
        }
        #pragma unroll
        for (int off = 32; off > 0; off >>= 1) {
            dflag += __shfl_down(dflag, off, 64);
            sflag += __shfl_down(sflag, off, 64);
        }
        if (lane == 0) {
            distp[b * 4 + w] = dflag;
            subp [b * 4 + w] = sflag;
        }
    }
}

// single block, 256 threads (one per row)
__global__ __launch_bounds__(256) void finalize_kernel(
    const int* __restrict__ partial,
    const int* __restrict__ subp,
    const int* __restrict__ distp,
    float* __restrict__ out)
{
    const int b = threadIdx.x;
    int gt = 0;
    #pragma unroll
    for (int s = 0; s < SLICES * 4; ++s) gt += partial[b * SLICES * 4 + s];
    int sub = 0, dist = 0;
    #pragma unroll
    for (int w = 0; w < 4; ++w) { sub += subp[b * 4 + w]; dist += distp[b * 4 + w]; }

    const float rank  = (float)(gt - sub);
    const float valid = (float)(V_CONST - dist);

    const float ks[5] = {1.0f, 5.0f, 10.0f, 20.0f, 50.0f};
    float vals[12];
    const float invlog = 1.0f / log2f(rank + 2.0f);
    #pragma unroll
    for (int i = 0; i < 5; ++i) {
        const float ind = (rank < ks[i]) ? 1.0f : 0.0f;
        vals[2 * i]     = ind * invlog;   // NDCG@k
        vals[2 * i + 1] = ind;            // Recall@k
    }
    vals[10] = 1.0f / (rank + 1.0f);      // MRR
    vals[11] = 1.0f - rank / valid;       // AUC-like

    __shared__ float red[4];
    for (int q = 0; q < 12; ++q) {
        float v = vals[q];
        #pragma unroll
        for (int off = 32; off > 0; off >>= 1)
            v += __shfl_down(v, off, 64);
        if ((b & 63) == 0) red[b >> 6] = v;
        __syncthreads();
        if (b == 0) out[q] = (red[0] + red[1] + red[2] + red[3]) * (1.0f / B_CONST);
        __syncthreads();
    }
    if (b == 0) out[12] = 0.0f;
}

extern "C" void kernel_launch(void* const* d_in, const int* in_sizes, int n_in,
                              void* d_out, int out_size, void* d_ws, size_t ws_size,
                              hipStream_t stream) {
    const float* scores = (const float*)d_in[0];
    const int*   labels = (const int*)d_in[1];
    const int*   seqs   = (const int*)d_in[2];
    float* out = (float*)d_out;
    int*   ws  = (int*)d_ws;

    int* partial = ws;                                       // B*SLICES*4
    int* subp    = ws + B_CONST * SLICES * 4;                // B*4
    int* distp   = ws + B_CONST * SLICES * 4 + B_CONST * 4;  // B*4

    rank_count_kernel<<<dim3(SLICES, B_CONST), 256, 0, stream>>>(
        scores, labels, seqs, partial, subp, distp);
    finalize_kernel<<<1, 256, 0, stream>>>(partial, subp, distp, out);
}